// Round 7
// baseline (3593.451 us; speedup 1.0000x reference)
//
#include <hip/hip_runtime.h>

#define NHID    1024
#define BATCH   128
#define LSTEPS  1000
#define DTC     0.042f
#define THETA   1.0f
#define TAUM    20.0f
#define LISTCAP 1032
#define CMP_STRIDE 1024          // bytes per compressed lif2hrf row
#define CMP_OFF    4096          // byte offset of compressed matrix inside d_ws
#define CMP_NEED   (CMP_OFF + (size_t)NHID * CMP_STRIDE + 64)

// ---------------- builder: compress lif2hrf (90% zeros) ----------------
// Row j -> [32 x {bits u32, prefix u32}] (256B) + packed nonzero values.
// Deterministic, runs every call (~10us). Skipping exact zeros is bit-exact
// for the consumer (adding 0.0f is identity; acc can never be -0.0).
__global__ __launch_bounds__(64) void build_cmp(const float* __restrict__ lif2hrf,
                                                unsigned int* __restrict__ cmp)
{
    const int j = blockIdx.x;
    const int l = threadIdx.x;
    __shared__ float row[NHID];
    __shared__ unsigned cnt[32];
    const float* src = lif2hrf + (size_t)j * NHID;
    for (int i = l; i < NHID; i += 64) row[i] = src[i];
    __syncthreads();
    unsigned int* dst = cmp + (size_t)j * (CMP_STRIDE / 4);
    unsigned bits = 0, c = 0;
    if (l < 32) {
        #pragma unroll
        for (int i = 0; i < 32; ++i)
            if (row[l * 32 + i] != 0.0f) { bits |= (1u << i); ++c; }
        cnt[l] = c;
    }
    __syncthreads();
    if (l < 32) {
        unsigned pre = 0;
        for (int i = 0; i < 32; ++i) pre += ((unsigned)i < (unsigned)l) ? cnt[i] : 0;
        dst[2 * l]     = bits;
        dst[2 * l + 1] = pre;
        unsigned idx = pre;
        for (int i = 0; i < 32; ++i) {
            const float v = row[l * 32 + i];
            if (v != 0.0f) {
                if (idx < 192) dst[64 + idx] = __float_as_uint(v);
                ++idx;
            }
        }
    }
}

// ---------------- main sim (R3 skeleton; phase C templated) ----------------
template<bool CMPQ>
__global__ __launch_bounds__(1024) void coesn_sim(
    const float* __restrict__ x,
    const float* __restrict__ x2h,
    const float* __restrict__ h2h,
    const float* __restrict__ bias,
    const float* __restrict__ lif2hrf,
    const float* __restrict__ gamma_,
    const float* __restrict__ eps_,
    const unsigned char* __restrict__ cmpb,   // compressed lif2hrf (CMPQ only)
    float* __restrict__ out,
    unsigned int* __restrict__ ws)
{
    const int b    = blockIdx.x;
    const int h    = threadIdx.x;
    const int wv   = h >> 6;
    const int lane = h & 63;

    __shared__ unsigned int Ls[LISTCAP];
    __shared__ unsigned int Ll[LISTCAP];
    __shared__ int Cs[16], Cl[16];
    __shared__ unsigned int red[16];

    Ls[h] = 0; Ll[h] = 0;
    if (h < LISTCAP - 1024) { Ls[1024 + h] = 0; Ll[1024 + h] = 0; }
    if (h < 16) { Cs[h] = 0; Cl[h] = 0; }

    float hy = 0.f, hz = 0.f, v = 0.f, rp = 0.f;
    float hysum = 0.f, hysq = 0.f;
    unsigned int chrf = 0, clif = 0;

    const float g    = gamma_[h];
    const float e    = eps_[h];
    const float bi   = bias[h];
    const float win  = x2h[h];
    const float ref_decay = expf((float)(-0.042 / 0.25));
    const float* xb  = x + (size_t)b * LSTEPS;

    const char* hb = (const char*)h2h     + 4 * (size_t)h;
    const char* lb = (const char*)lif2hrf + 4 * (size_t)h;

    const unsigned long long below = (1ULL << lane) - 1ULL;
    const unsigned mslot   = 8u * (unsigned)(h >> 5);
    const unsigned bitm    = 1u << (h & 31);
    const unsigned below32 = bitm - 1u;

    int ns = 0;

    __syncthreads();

    for (int t = 0; t < LSTEPS; ++t) {
        // ---- phase A: cur = x*x2h + bias + sum of spiking h2h rows (dense) ----
        const float xv = xb[t];
        float cur = xv * win + bi;
        for (int k = 0; k < ns; k += 8) {
            const unsigned o0 = Ls[k+0], o1 = Ls[k+1], o2 = Ls[k+2], o3 = Ls[k+3];
            const unsigned o4 = Ls[k+4], o5 = Ls[k+5], o6 = Ls[k+6], o7 = Ls[k+7];
            const float a0 = *(const float*)(hb + o0);
            const float a1 = *(const float*)(hb + o1);
            const float a2 = *(const float*)(hb + o2);
            const float a3 = *(const float*)(hb + o3);
            const float a4 = *(const float*)(hb + o4);
            const float a5 = *(const float*)(hb + o5);
            const float a6 = *(const float*)(hb + o6);
            const float a7 = *(const float*)(hb + o7);
            cur += a0;
            cur += (k+1 < ns) ? a1 : 0.0f;
            cur += (k+2 < ns) ? a2 : 0.0f;
            cur += (k+3 < ns) ? a3 : 0.0f;
            cur += (k+4 < ns) ? a4 : 0.0f;
            cur += (k+5 < ns) ? a5 : 0.0f;
            cur += (k+6 < ns) ? a6 : 0.0f;
            cur += (k+7 < ns) ? a7 : 0.0f;
        }

        // ---- phase B: LIF update + spike + list build ----
        v = v + DTC * (-v / TAUM + cur);
        const float lsp = (v > THETA) ? 1.f : 0.f;
        v -= lsp * THETA;
        clif += (unsigned)lsp;
        const unsigned long long balL = __ballot(lsp > 0.5f);
        if (lane == 0) Cl[wv] = (int)__popcll(balL);
        __syncthreads();
        int pre = 0, nl = 0;
        #pragma unroll
        for (int i = 0; i < 16; ++i) { const int ci = Cl[i]; nl += ci; pre += (i < wv) ? ci : 0; }
        if (lsp > 0.5f)
            Ll[pre + (int)__popcll(balL & below)] = (unsigned)(h * (CMPQ ? CMP_STRIDE : 4096));
        __syncthreads();

        // ---- phase C: drive = sum of spiking lif2hrf rows ----
        float dr = 0.f;
        if (CMPQ) {
            if (nl > 0) {
                unsigned off[8];
                unsigned long long m[8];
                #pragma unroll
                for (int i = 0; i < 8; ++i) off[i] = Ll[i];
                #pragma unroll
                for (int i = 0; i < 8; ++i)
                    m[i] = *(const unsigned long long*)(cmpb + off[i] + mslot);
                for (int k = 0; k < nl; k += 8) {
                    unsigned noff[8];
                    unsigned long long nm[8];
                    if (k + 8 < nl) {                       // wave-uniform
                        #pragma unroll
                        for (int i = 0; i < 8; ++i) noff[i] = Ll[k + 8 + i];
                        #pragma unroll
                        for (int i = 0; i < 8; ++i)
                            nm[i] = *(const unsigned long long*)(cmpb + noff[i] + mslot);
                    } else {
                        #pragma unroll
                        for (int i = 0; i < 8; ++i) { noff[i] = off[i]; nm[i] = m[i]; }
                    }
                    float val[8];
                    #pragma unroll
                    for (int i = 0; i < 8; ++i) {
                        const unsigned bits = (unsigned)m[i];
                        const unsigned pfx  = (unsigned)(m[i] >> 32);
                        const unsigned idx  = pfx + (unsigned)__popc(bits & below32);
                        val[i] = *(const float*)(cmpb + off[i] + 256u + 4u * idx);
                    }
                    #pragma unroll
                    for (int i = 0; i < 8; ++i) {
                        const bool hit = ((unsigned)m[i] & bitm) != 0u;
                        dr += ((k + i < nl) && hit) ? val[i] : 0.0f;
                    }
                    #pragma unroll
                    for (int i = 0; i < 8; ++i) { off[i] = noff[i]; m[i] = nm[i]; }
                }
            }
        } else {
            for (int k = 0; k < nl; k += 8) {
                const unsigned o0 = Ll[k+0], o1 = Ll[k+1], o2 = Ll[k+2], o3 = Ll[k+3];
                const unsigned o4 = Ll[k+4], o5 = Ll[k+5], o6 = Ll[k+6], o7 = Ll[k+7];
                const float a0 = *(const float*)(lb + o0);
                const float a1 = *(const float*)(lb + o1);
                const float a2 = *(const float*)(lb + o2);
                const float a3 = *(const float*)(lb + o3);
                const float a4 = *(const float*)(lb + o4);
                const float a5 = *(const float*)(lb + o5);
                const float a6 = *(const float*)(lb + o6);
                const float a7 = *(const float*)(lb + o7);
                dr += a0;
                dr += (k+1 < nl) ? a1 : 0.0f;
                dr += (k+2 < nl) ? a2 : 0.0f;
                dr += (k+3 < nl) ? a3 : 0.0f;
                dr += (k+4 < nl) ? a4 : 0.0f;
                dr += (k+5 < nl) ? a5 : 0.0f;
                dr += (k+6 < nl) ? a6 : 0.0f;
                dr += (k+7 < nl) ? a7 : 0.0f;
            }
        }

        // ---- phase D: HRF update + spike + stats + list build ----
        hz = hz + DTC * (dr - g * hy - e * hz);
        hy = hy + DTC * hz;
        const float sn = ((hy - THETA - rp) > 0.f) ? 1.f : 0.f;
        rp = rp * ref_decay + sn;
        hysum += hy;
        hysq  += hy * hy;
        chrf += (unsigned)sn;
        const unsigned long long balS = __ballot(sn > 0.5f);
        if (lane == 0) Cs[wv] = (int)__popcll(balS);
        __syncthreads();
        pre = 0; ns = 0;
        #pragma unroll
        for (int i = 0; i < 16; ++i) { const int ci = Cs[i]; ns += ci; pre += (i < wv) ? ci : 0; }
        if (sn > 0.5f) Ls[pre + (int)__popcll(balS & below)] = (unsigned)(h * 4096);
        __syncthreads();
    }

    // ---- epilogue: features ----
    const float Lf   = (float)LSTEPS;
    const float mean = hysum / Lf;
    const float rms  = sqrtf(hysq / Lf + 1e-8f);
    float var = hysq / Lf - mean * mean;
    var = fmaxf(var, 1e-8f);
    float* ob = out + (size_t)b * (3 * NHID);
    ob[h]            = rms;
    ob[NHID + h]     = sqrtf(var);
    ob[2 * NHID + h] = hy;

    // ---- spike-count reduction (exact ints) ----
    unsigned int c = chrf;
    for (int off = 32; off > 0; off >>= 1) c += __shfl_down(c, off, 64);
    if (lane == 0) red[wv] = c;
    __syncthreads();
    if (h == 0) {
        unsigned int tot = 0;
        for (int i = 0; i < 16; ++i) tot += red[i];
        ws[b * 2] = tot;
    }
    __syncthreads();
    c = clif;
    for (int off = 32; off > 0; off >>= 1) c += __shfl_down(c, off, 64);
    if (lane == 0) red[wv] = c;
    __syncthreads();
    if (h == 0) {
        unsigned int tot = 0;
        for (int i = 0; i < 16; ++i) tot += red[i];
        ws[b * 2 + 1] = tot;
    }
}

__global__ void coesn_final(const unsigned int* __restrict__ ws,
                            float* __restrict__ out)
{
    if (threadIdx.x == 0 && blockIdx.x == 0) {
        unsigned long long hrf = 0, lif = 0;
        for (int b = 0; b < BATCH; ++b) {
            hrf += ws[b * 2];
            lif += ws[b * 2 + 1];
        }
        const float denom = (float)BATCH * (float)LSTEPS * (float)NHID;
        const float r_hrf = (float)hrf / denom;
        const float r_lif = (float)lif / denom;
        float* s = out + (size_t)BATCH * 3 * NHID;
        s[0] = r_hrf;
        s[1] = r_hrf;
        s[2] = r_lif;
    }
}

extern "C" void kernel_launch(void* const* d_in, const int* in_sizes, int n_in,
                              void* d_out, int out_size, void* d_ws, size_t ws_size,
                              hipStream_t stream) {
    const float* x       = (const float*)d_in[0];
    const float* x2h     = (const float*)d_in[1];
    const float* h2h     = (const float*)d_in[2];
    const float* bias    = (const float*)d_in[3];
    const float* lif2hrf = (const float*)d_in[4];
    const float* gamma_  = (const float*)d_in[5];
    const float* eps_    = (const float*)d_in[6];
    float* out = (float*)d_out;
    unsigned int* wsp = (unsigned int*)d_ws;

    if (ws_size >= CMP_NEED) {
        unsigned int* cmp = (unsigned int*)((char*)d_ws + CMP_OFF);
        build_cmp<<<NHID, 64, 0, stream>>>(lif2hrf, cmp);
        coesn_sim<true><<<BATCH, NHID, 0, stream>>>(x, x2h, h2h, bias, lif2hrf,
                                                    gamma_, eps_,
                                                    (const unsigned char*)cmp, out, wsp);
    } else {
        coesn_sim<false><<<BATCH, NHID, 0, stream>>>(x, x2h, h2h, bias, lif2hrf,
                                                     gamma_, eps_, nullptr, out, wsp);
    }
    coesn_final<<<1, 64, 0, stream>>>(wsp, out);
}

// Round 8
// 1760.542 us; speedup vs baseline: 2.0411x; 2.0411x over previous
//
#include <hip/hip_runtime.h>

#define NHID    1024
#define BATCH   128
#define LSTEPS  1000
#define DTC     0.042f
#define THETA   1.0f
#define TAUM    20.0f
#define LISTCAP 1040          // 1024 + pad (multiple of 16B for uint4 reads)

// Two-deep pipelined sparse row gather. Offsets come from LDS as uint4
// (16B-aligned; k is a multiple of 8 so (k>>2) is even). Chunk k+1's offset
// reads + global loads are issued BEFORE chunk k's adds, so only the first
// load latency per phase is exposed. Accumulation order is strictly
// ascending k with R3's exact predication pattern -> bit-identical numerics.
// Stale list entries (>= n) are zero offsets -> in-range row-0 loads, and
// their adds are predicated to +0.0f (exact identity).
__device__ __forceinline__ float gather8p(float acc, const char* __restrict__ colbase,
                                          const uint4* __restrict__ L4, int n)
{
    if (n <= 0) return acc;
    uint4 pa = L4[0], pb = L4[1];
    float v0 = *(const float*)(colbase + pa.x);
    float v1 = *(const float*)(colbase + pa.y);
    float v2 = *(const float*)(colbase + pa.z);
    float v3 = *(const float*)(colbase + pa.w);
    float v4 = *(const float*)(colbase + pb.x);
    float v5 = *(const float*)(colbase + pb.y);
    float v6 = *(const float*)(colbase + pb.z);
    float v7 = *(const float*)(colbase + pb.w);
    int k = 0;
    #pragma unroll 1
    for (; k + 8 < n; k += 8) {
        const uint4 na = L4[(k >> 2) + 2];
        const uint4 nb = L4[(k >> 2) + 3];
        const float w0 = *(const float*)(colbase + na.x);
        const float w1 = *(const float*)(colbase + na.y);
        const float w2 = *(const float*)(colbase + na.z);
        const float w3 = *(const float*)(colbase + na.w);
        const float w4 = *(const float*)(colbase + nb.x);
        const float w5 = *(const float*)(colbase + nb.y);
        const float w6 = *(const float*)(colbase + nb.z);
        const float w7 = *(const float*)(colbase + nb.w);
        acc += v0; acc += v1; acc += v2; acc += v3;
        acc += v4; acc += v5; acc += v6; acc += v7;
        v0 = w0; v1 = w1; v2 = w2; v3 = w3;
        v4 = w4; v5 = w5; v6 = w6; v7 = w7;
    }
    acc += v0;
    acc += (k + 1 < n) ? v1 : 0.0f;
    acc += (k + 2 < n) ? v2 : 0.0f;
    acc += (k + 3 < n) ? v3 : 0.0f;
    acc += (k + 4 < n) ? v4 : 0.0f;
    acc += (k + 5 < n) ? v5 : 0.0f;
    acc += (k + 6 < n) ? v6 : 0.0f;
    acc += (k + 7 < n) ? v7 : 0.0f;
    return acc;
}

// One block per batch element; thread h owns hidden unit h. 16 waves/CU,
// 1 block/CU (grid 128). launch_bounds(1024,4) -> ~128 VGPR budget so the
// pipeline registers do NOT spill to scratch (the R4/R5 failure mode).
__global__ __launch_bounds__(1024, 4) void coesn_sim(
    const float* __restrict__ x,        // (B, L, 1)
    const float* __restrict__ x2h,      // (1, H)
    const float* __restrict__ h2h,      // (H, H)
    const float* __restrict__ bias,     // (H)
    const float* __restrict__ lif2hrf,  // (H, H)
    const float* __restrict__ gamma_,   // (H)
    const float* __restrict__ eps_,     // (H)
    float* __restrict__ out,            // (B, 3H) features
    unsigned int* __restrict__ ws)      // (B, 2) spike counts
{
    const int b    = blockIdx.x;
    const int h    = threadIdx.x;
    const int wv   = h >> 6;
    const int lane = h & 63;
    const int wvs  = __builtin_amdgcn_readfirstlane(wv);

    __shared__ unsigned int Ls[LISTCAP];   // HRF spike row byte-offsets
    __shared__ unsigned int Ll[LISTCAP];   // LIF spike row byte-offsets
    __shared__ int Cs[16], Cl[16];
    __shared__ unsigned int red[16];

    Ls[h] = 0; Ll[h] = 0;                  // stale entries stay in-range forever
    if (h < LISTCAP - 1024) { Ls[1024 + h] = 0; Ll[1024 + h] = 0; }
    if (h < 16) { Cs[h] = 0; Cl[h] = 0; }

    float hy = 0.f, hz = 0.f, v = 0.f, rp = 0.f;
    float hysum = 0.f, hysq = 0.f;
    unsigned int chrf = 0, clif = 0;

    const float g    = gamma_[h];
    const float e    = eps_[h];
    const float bi   = bias[h];
    const float win  = x2h[h];
    const float ref_decay = expf((float)(-0.042 / 0.25));
    const float* xb  = x + (size_t)b * LSTEPS;

    const char* hb = (const char*)h2h     + 4 * (size_t)h;
    const char* lb = (const char*)lif2hrf + 4 * (size_t)h;
    const uint4* Ls4 = (const uint4*)Ls;
    const uint4* Ll4 = (const uint4*)Ll;

    const unsigned long long below = (1ULL << lane) - 1ULL;

    int ns = 0;   // HRF list length (phase A bound); 0 at t=0

    __syncthreads();

    for (int t = 0; t < LSTEPS; ++t) {
        // ---- phase A: cur = x*x2h + bias + sum of spiking h2h rows ----
        const float xv = xb[t];
        const float cur = gather8p(xv * win + bi, hb, Ls4, ns);

        // ---- phase B: LIF update + spike + list build ----
        v = v + DTC * (-v / TAUM + cur);
        const float lsp = (v > THETA) ? 1.f : 0.f;
        v -= lsp * THETA;
        clif += (unsigned)lsp;
        const unsigned long long balL = __ballot(lsp > 0.5f);
        if (lane == 0) Cl[wv] = (int)__popcll(balL);
        __syncthreads();
        int cv = Cl[lane & 15];
        int pre = 0, nl = 0;
        #pragma unroll
        for (int i = 0; i < 16; ++i) {
            const int ci = __builtin_amdgcn_readlane(cv, i);
            nl += ci;
            pre += (i < wvs) ? ci : 0;
        }
        if (lsp > 0.5f) Ll[pre + (int)__popcll(balL & below)] = (unsigned)(h * 4096);
        __syncthreads();

        // ---- phase C: drive = sum of spiking lif2hrf rows ----
        const float dr = gather8p(0.0f, lb, Ll4, nl);

        // ---- phase D: HRF update + spike + stats + list build ----
        hz = hz + DTC * (dr - g * hy - e * hz);
        hy = hy + DTC * hz;
        const float sn = ((hy - THETA - rp) > 0.f) ? 1.f : 0.f;
        rp = rp * ref_decay + sn;
        hysum += hy;
        hysq  += hy * hy;
        chrf += (unsigned)sn;
        const unsigned long long balS = __ballot(sn > 0.5f);
        if (lane == 0) Cs[wv] = (int)__popcll(balS);
        __syncthreads();
        cv = Cs[lane & 15];
        pre = 0; ns = 0;
        #pragma unroll
        for (int i = 0; i < 16; ++i) {
            const int ci = __builtin_amdgcn_readlane(cv, i);
            ns += ci;
            pre += (i < wvs) ? ci : 0;
        }
        if (sn > 0.5f) Ls[pre + (int)__popcll(balS & below)] = (unsigned)(h * 4096);
        __syncthreads();
    }

    // ---- epilogue: features ----
    const float Lf   = (float)LSTEPS;
    const float mean = hysum / Lf;
    const float rms  = sqrtf(hysq / Lf + 1e-8f);
    float var = hysq / Lf - mean * mean;
    var = fmaxf(var, 1e-8f);
    float* ob = out + (size_t)b * (3 * NHID);
    ob[h]            = rms;
    ob[NHID + h]     = sqrtf(var);
    ob[2 * NHID + h] = hy;

    // ---- spike-count reduction (exact ints) ----
    unsigned int c = chrf;
    for (int off = 32; off > 0; off >>= 1) c += __shfl_down(c, off, 64);
    if (lane == 0) red[wv] = c;
    __syncthreads();
    if (h == 0) {
        unsigned int tot = 0;
        for (int i = 0; i < 16; ++i) tot += red[i];
        ws[b * 2] = tot;
    }
    __syncthreads();
    c = clif;
    for (int off = 32; off > 0; off >>= 1) c += __shfl_down(c, off, 64);
    if (lane == 0) red[wv] = c;
    __syncthreads();
    if (h == 0) {
        unsigned int tot = 0;
        for (int i = 0; i < 16; ++i) tot += red[i];
        ws[b * 2 + 1] = tot;
    }
}

__global__ void coesn_final(const unsigned int* __restrict__ ws,
                            float* __restrict__ out)
{
    if (threadIdx.x == 0 && blockIdx.x == 0) {
        unsigned long long hrf = 0, lif = 0;
        for (int b = 0; b < BATCH; ++b) {
            hrf += ws[b * 2];
            lif += ws[b * 2 + 1];
        }
        const float denom = (float)BATCH * (float)LSTEPS * (float)NHID;
        const float r_hrf = (float)hrf / denom;
        const float r_lif = (float)lif / denom;
        float* s = out + (size_t)BATCH * 3 * NHID;
        s[0] = r_hrf;
        s[1] = r_hrf;
        s[2] = r_lif;
    }
}

extern "C" void kernel_launch(void* const* d_in, const int* in_sizes, int n_in,
                              void* d_out, int out_size, void* d_ws, size_t ws_size,
                              hipStream_t stream) {
    const float* x       = (const float*)d_in[0];
    const float* x2h     = (const float*)d_in[1];
    const float* h2h     = (const float*)d_in[2];
    const float* bias    = (const float*)d_in[3];
    const float* lif2hrf = (const float*)d_in[4];
    const float* gamma_  = (const float*)d_in[5];
    const float* eps_    = (const float*)d_in[6];
    float* out = (float*)d_out;
    unsigned int* wsp = (unsigned int*)d_ws;

    coesn_sim<<<BATCH, NHID, 0, stream>>>(x, x2h, h2h, bias, lif2hrf, gamma_, eps_, out, wsp);
    coesn_final<<<1, 64, 0, stream>>>(wsp, out);
}

// Round 9
// 1512.379 us; speedup vs baseline: 2.3760x; 1.1641x over previous
//
#include <hip/hip_runtime.h>

#define NHID    1024
#define BATCH   128
#define LSTEPS  1000
#define DTC     0.042f
#define THETA   1.0f
#define TAUM    20.0f
#define LISTCAP 1032

// One block per batch element; thread h owns hidden unit h (16 waves/CU).
// Binary-spike matmuls = sparse row gathers over ONE combined LDS offset list
// per phase (ascending j -> f32 add order identical to R1/R3). Prefix across
// the 16 waves is a 16-lane shfl scan (no 16-iter LDS loop); n and pre are
// wave-uniform SGPRs.
__global__ __launch_bounds__(1024) void coesn_sim(
    const float* __restrict__ x,        // (B, L, 1)
    const float* __restrict__ x2h,      // (1, H)
    const float* __restrict__ h2h,      // (H, H)
    const float* __restrict__ bias,     // (H)
    const float* __restrict__ lif2hrf,  // (H, H)
    const float* __restrict__ gamma_,   // (H)
    const float* __restrict__ eps_,     // (H)
    float* __restrict__ out,            // (B, 3H) features
    unsigned int* __restrict__ ws)      // (B, 2) spike counts
{
    const int b    = blockIdx.x;
    const int h    = threadIdx.x;
    const int wv   = h >> 6;
    const int lane = h & 63;
    const int wvs  = __builtin_amdgcn_readfirstlane(wv);

    __shared__ unsigned int Ls[LISTCAP];  // HRF spike row byte-offsets
    __shared__ unsigned int Ll[LISTCAP];  // LIF spike row byte-offsets
    __shared__ int Cs[16], Cl[16];
    __shared__ unsigned int red[16];

    Ls[h] = 0; Ll[h] = 0;                 // stale entries stay in-range forever
    if (h < LISTCAP - 1024) { Ls[1024 + h] = 0; Ll[1024 + h] = 0; }
    if (h < 16) { Cs[h] = 0; Cl[h] = 0; }

    float hy = 0.f, hz = 0.f, v = 0.f, rp = 0.f;
    float hysum = 0.f, hysq = 0.f;
    unsigned int chrf = 0, clif = 0;

    const float g    = gamma_[h];
    const float e    = eps_[h];
    const float bi   = bias[h];
    const float win  = x2h[h];
    const float ref_decay = expf((float)(-0.042 / 0.25));
    const float* xb  = x + (size_t)b * LSTEPS;

    const char* hb = (const char*)h2h     + 4 * (size_t)h;
    const char* lb = (const char*)lif2hrf + 4 * (size_t)h;

    const unsigned long long below = (1ULL << lane) - 1ULL;
    const int l16 = lane & 15;

    int ns = 0;                 // HRF list length (phase A bound); 0 at t=0
    float xv_next = xb[0];      // x prefetch (one step ahead)

    __syncthreads();

    for (int t = 0; t < LSTEPS; ++t) {
        // ---- phase A: cur = x*x2h + bias + sum of spiking h2h rows ----
        const float xv = xv_next;
        xv_next = xb[(t + 1 < LSTEPS) ? (t + 1) : t];   // issues early, used next step
        float cur = xv * win + bi;
        for (int k = 0; k < ns; k += 8) {
            const unsigned o0 = Ls[k+0], o1 = Ls[k+1], o2 = Ls[k+2], o3 = Ls[k+3];
            const unsigned o4 = Ls[k+4], o5 = Ls[k+5], o6 = Ls[k+6], o7 = Ls[k+7];
            const float a0 = *(const float*)(hb + o0);
            const float a1 = *(const float*)(hb + o1);
            const float a2 = *(const float*)(hb + o2);
            const float a3 = *(const float*)(hb + o3);
            const float a4 = *(const float*)(hb + o4);
            const float a5 = *(const float*)(hb + o5);
            const float a6 = *(const float*)(hb + o6);
            const float a7 = *(const float*)(hb + o7);
            cur += a0;
            cur += (k+1 < ns) ? a1 : 0.0f;
            cur += (k+2 < ns) ? a2 : 0.0f;
            cur += (k+3 < ns) ? a3 : 0.0f;
            cur += (k+4 < ns) ? a4 : 0.0f;
            cur += (k+5 < ns) ? a5 : 0.0f;
            cur += (k+6 < ns) ? a6 : 0.0f;
            cur += (k+7 < ns) ? a7 : 0.0f;
        }

        // ---- phase B: LIF update + spike + list build ----
        v = v + DTC * (-v / TAUM + cur);
        const float lsp = (v > THETA) ? 1.f : 0.f;
        v -= lsp * THETA;
        clif += (unsigned)lsp;
        const unsigned long long balL = __ballot(lsp > 0.5f);
        if (lane == 0) Cl[wv] = (int)__popcll(balL);
        __syncthreads();
        // 16-lane shfl scan of counts (all waves compute the same scan)
        int cv = Cl[l16];
        int incl = cv;
        #pragma unroll
        for (int d = 1; d < 16; d <<= 1) {
            const int tt = __shfl_up(incl, d, 16);
            incl += (l16 >= d) ? tt : 0;
        }
        int nl  = __builtin_amdgcn_readlane(incl, 15);
        int pre = __builtin_amdgcn_readlane(incl - cv, wvs);
        if (lsp > 0.5f) Ll[pre + (int)__popcll(balL & below)] = (unsigned)(h * 4096);
        __syncthreads();

        // ---- phase C: drive = sum of spiking lif2hrf rows ----
        float dr = 0.f;
        for (int k = 0; k < nl; k += 8) {
            const unsigned o0 = Ll[k+0], o1 = Ll[k+1], o2 = Ll[k+2], o3 = Ll[k+3];
            const unsigned o4 = Ll[k+4], o5 = Ll[k+5], o6 = Ll[k+6], o7 = Ll[k+7];
            const float a0 = *(const float*)(lb + o0);
            const float a1 = *(const float*)(lb + o1);
            const float a2 = *(const float*)(lb + o2);
            const float a3 = *(const float*)(lb + o3);
            const float a4 = *(const float*)(lb + o4);
            const float a5 = *(const float*)(lb + o5);
            const float a6 = *(const float*)(lb + o6);
            const float a7 = *(const float*)(lb + o7);
            dr += a0;
            dr += (k+1 < nl) ? a1 : 0.0f;
            dr += (k+2 < nl) ? a2 : 0.0f;
            dr += (k+3 < nl) ? a3 : 0.0f;
            dr += (k+4 < nl) ? a4 : 0.0f;
            dr += (k+5 < nl) ? a5 : 0.0f;
            dr += (k+6 < nl) ? a6 : 0.0f;
            dr += (k+7 < nl) ? a7 : 0.0f;
        }

        // ---- phase D: HRF update + spike + stats + list build ----
        hz = hz + DTC * (dr - g * hy - e * hz);
        hy = hy + DTC * hz;
        const float sn = ((hy - THETA - rp) > 0.f) ? 1.f : 0.f;
        rp = rp * ref_decay + sn;
        hysum += hy;
        hysq  += hy * hy;
        chrf += (unsigned)sn;
        const unsigned long long balS = __ballot(sn > 0.5f);
        if (lane == 0) Cs[wv] = (int)__popcll(balS);
        __syncthreads();
        cv = Cs[l16];
        incl = cv;
        #pragma unroll
        for (int d = 1; d < 16; d <<= 1) {
            const int tt = __shfl_up(incl, d, 16);
            incl += (l16 >= d) ? tt : 0;
        }
        ns  = __builtin_amdgcn_readlane(incl, 15);
        pre = __builtin_amdgcn_readlane(incl - cv, wvs);
        if (sn > 0.5f) Ls[pre + (int)__popcll(balS & below)] = (unsigned)(h * 4096);
        __syncthreads();
    }

    // ---- epilogue: features ----
    const float Lf   = (float)LSTEPS;
    const float mean = hysum / Lf;
    const float rms  = sqrtf(hysq / Lf + 1e-8f);
    float var = hysq / Lf - mean * mean;
    var = fmaxf(var, 1e-8f);
    float* ob = out + (size_t)b * (3 * NHID);
    ob[h]            = rms;
    ob[NHID + h]     = sqrtf(var);
    ob[2 * NHID + h] = hy;

    // ---- spike-count reduction (exact ints) ----
    unsigned int c = chrf;
    for (int off = 32; off > 0; off >>= 1) c += __shfl_down(c, off, 64);
    if (lane == 0) red[wv] = c;
    __syncthreads();
    if (h == 0) {
        unsigned int tot = 0;
        for (int i = 0; i < 16; ++i) tot += red[i];
        ws[b * 2] = tot;
    }
    __syncthreads();
    c = clif;
    for (int off = 32; off > 0; off >>= 1) c += __shfl_down(c, off, 64);
    if (lane == 0) red[wv] = c;
    __syncthreads();
    if (h == 0) {
        unsigned int tot = 0;
        for (int i = 0; i < 16; ++i) tot += red[i];
        ws[b * 2 + 1] = tot;
    }
}

__global__ void coesn_final(const unsigned int* __restrict__ ws,
                            float* __restrict__ out)
{
    if (threadIdx.x == 0 && blockIdx.x == 0) {
        unsigned long long hrf = 0, lif = 0;
        for (int b = 0; b < BATCH; ++b) {
            hrf += ws[b * 2];
            lif += ws[b * 2 + 1];
        }
        const float denom = (float)BATCH * (float)LSTEPS * (float)NHID;
        const float r_hrf = (float)hrf / denom;
        const float r_lif = (float)lif / denom;
        float* s = out + (size_t)BATCH * 3 * NHID;
        s[0] = r_hrf;
        s[1] = r_hrf;
        s[2] = r_lif;
    }
}

extern "C" void kernel_launch(void* const* d_in, const int* in_sizes, int n_in,
                              void* d_out, int out_size, void* d_ws, size_t ws_size,
                              hipStream_t stream) {
    const float* x       = (const float*)d_in[0];
    const float* x2h     = (const float*)d_in[1];
    const float* h2h     = (const float*)d_in[2];
    const float* bias    = (const float*)d_in[3];
    const float* lif2hrf = (const float*)d_in[4];
    const float* gamma_  = (const float*)d_in[5];
    const float* eps_    = (const float*)d_in[6];
    float* out = (float*)d_out;
    unsigned int* wsp = (unsigned int*)d_ws;

    coesn_sim<<<BATCH, NHID, 0, stream>>>(x, x2h, h2h, bias, lif2hrf, gamma_, eps_, out, wsp);
    coesn_final<<<1, 64, 0, stream>>>(wsp, out);
}